// Round 17
// baseline (248.426 us; speedup 1.0000x reference)
//
#include <hip/hip_runtime.h>
#include <hip/hip_bf16.h>

typedef __attribute__((ext_vector_type(8))) __bf16 bf16x8;
typedef __attribute__((ext_vector_type(4))) float  f32x4;

#define SDIM 49
#define NDIM 1024
#define CDIM 384
#define DDIM 512
#define DMC  64
#define SCALE (1.0f/(SDIM*NDIM))
#define SLOT3 24576  // per K-step slot: A 256x64B (16K) + B 128x64B (8K); 3 slots = 72KB
#define CHUNK 12288  // floats copied per tile: 3136*12288 == 2*1024*384*49

__device__ __forceinline__ void gload16(const void* g, void* l) {
    __builtin_amdgcn_global_load_lds((const __attribute__((address_space(1))) void*)g,
                                     (__attribute__((address_space(3))) void*)l, 16, 0, 0);
}

// ---------------------------------------------------------------------------
// fused front kernel (validated R16): both packs + f conversion + out[0] zero.
// ---------------------------------------------------------------------------
__global__ __launch_bounds__(512) void front_kernel(
    const float* __restrict__ xp, const float* __restrict__ mp,
    const float* __restrict__ cp, __hip_bfloat16* __restrict__ Km,
    const float* __restrict__ x,  const float* __restrict__ mt,
    const float* __restrict__ ct, __hip_bfloat16* __restrict__ Qm,
    const float* __restrict__ f,  __hip_bfloat16* __restrict__ Fm,
    float* __restrict__ out0)
{
    const int bid = blockIdx.x;
    const int tid = threadIdx.x;

    if (tid < 256) {
        const int i = bid * 256 + tid;
        Fm[i] = __float2bfloat16(f[i]);
    }
    if (bid == 0 && tid == 0) out0[0] = 0.0f;

    const bool kside = (bid < 1024);
    const int j = kside ? bid : (bid - 1024);
    const float* xloc = kside ? xp : x;
    const float* mv   = kside ? mp : mt;
    const float* cv   = kside ? cp : ct;
    __hip_bfloat16* dst = kside ? Km : Qm;

    const int d = tid;
    float vals[SDIM];
    if (d < CDIM) {
        const float* p = xloc + ((size_t)j * CDIM + d) * SDIM;
        #pragma unroll
        for (int s = 0; s < SDIM; ++s) vals[s] = p[s];
    } else if (d < CDIM + DMC) {
        float v = mv[j * DMC + (d - CDIM)];
        #pragma unroll
        for (int s = 0; s < SDIM; ++s) vals[s] = v;
    } else {
        float v = cv[j * DMC + (d - CDIM - DMC)];
        #pragma unroll
        for (int s = 0; s < SDIM; ++s) vals[s] = v;
    }
    #pragma unroll
    for (int s = 0; s < SDIM; ++s)
        dst[((size_t)s * NDIM + j) * DDIM + d] = __float2bfloat16(vals[s]);
}

// ---------------------------------------------------------------------------
// PERSISTENT fused GEMM + partial-LSE + hidden copy, counted 3-slot ring,
// 2 BLOCKS/CU CO-RESIDENT (reg-light waves).
// grid = 512 blocks of 512 (= exactly 2/CU); block (xcd=bid&7, jj=bid>>3)
// owns tiles l = jj + 64k (l < 392), g = 392*xcd + l (6-7 tiles).
// Tile g: s=g>>6, kb=(g>>4)&3, qb=g&15 (qb<8: Fm rows qb*128; else Qm).
// Tile: 256 keys x 128 q, BK=32 (16 K-steps); 8 waves = 4 wk x 2 wq,
// wave-tile 64 keys x 64 q -> acc[4][4] f32x4 = 64 VGPR (<=128 total,
// launch_bounds(512,4) => 4 waves/SIMD => both blocks resident).
// MFMA 16x16x32 bf16; C/D col=lane&15, row=(lane>>4)*4+reg (validated).
// LDS slot (24KB): A rows [256][64B] @0, B rows [128][64B] @16K.
// Swizzle (validated R15): (row,o) holds k-octet ((o>>4)-((row>>1)&3))&3;
// read at o=((l4+(l15>>1))&3)<<4; staged linear dest + source col
// jcol=(((tid&3)-((tid>>3)&3))&3)<<4.  2-way bank aliasing = free.
// Step: vmcnt(3) [slot-t loads 2 steps old - counted, never fresh; final
// tile t=15: vmcnt(0)]; s_barrier; stage3(step+2) [t>=14: next tile steps
// 0/1 - ring slot runs mod 3 continuously across tiles]; 8 ds_read; 16 MFMA.
// Epilogue: cbuf copy (12288 floats/tile), LSE, diag, part (16 slots/row).
// ---------------------------------------------------------------------------
__global__ __launch_bounds__(512, 4) void loss_kernel(
    const __hip_bfloat16* __restrict__ Fm,   // [N,512]
    const __hip_bfloat16* __restrict__ Km,   // [S,N,512] keys
    const __hip_bfloat16* __restrict__ Qm,   // [S,N,512] queries (pred2)
    const float* __restrict__ xp,            // copy source 1
    const float* __restrict__ xq,            // copy source 2
    float* __restrict__ outv,                // out+1 (copy dest)
    float2* __restrict__ part,               // [S*2048][16]
    float* __restrict__ out)
{
    extern __shared__ __attribute__((aligned(16))) char sm[];   // 3*SLOT3

    const int bid = blockIdx.x;
    const int xcd = bid & 7;
    const int jj  = bid >> 3;

    const int tid  = threadIdx.x;
    const int lane = tid & 63;
    const int w    = tid >> 6;
    const int l15  = lane & 15;
    const int l4   = lane >> 4;   // 0..3
    const int wk   = w >> 1;      // 0..3 key quarter (64 keys)
    const int wq   = w & 1;       // 0..1 q half (64 q)

    const int jcol = (((tid & 3) - ((tid >> 3) & 3)) & 3) << 4;

    const unsigned off   = (unsigned)(((l4 + (l15 >> 1)) & 3) << 4);
    const unsigned abase = (unsigned)((wk * 64 + l15) * 64);
    const unsigned bbase = 16384u + (unsigned)((wq * 64 + l15) * 64);

    auto APtr = [&](int g) -> const char* {
        const int s = g >> 6, kb = (g >> 4) & 3;
        return (const char*)Km + ((size_t)s * NDIM + (size_t)kb * 256) * 1024;
    };
    auto BPtr = [&](int g) -> const char* {
        const int s = g >> 6, qb = g & 15;
        return (qb < 8)
            ? ((const char*)Fm + (size_t)qb * 128 * 1024)
            : ((const char*)Qm + ((size_t)s * NDIM + (size_t)(qb - 8) * 128) * 1024);
    };
    // stage one BK=32 K-step: A 2 rounds + B 1 round = 3 gloads/thread
    auto stage3 = [&](const char* A, const char* B, int ko, char* slot) {
        const int r = tid >> 2;
        gload16(A + (size_t)r * 1024 + ko + jcol,        slot + tid * 16);
        gload16(A + (size_t)(128 + r) * 1024 + ko + jcol, slot + 8192 + tid * 16);
        gload16(B + (size_t)r * 1024 + ko + jcol,        slot + 16384 + tid * 16);
    };

    f32x4 acc[4][4];
    bf16x8 afr[4], bfr[4];

    #define READ8() do {                                                      \
        _Pragma("unroll")                                                     \
        for (int a = 0; a < 4; ++a)                                           \
            afr[a] = *(const bf16x8*)(sb_ + abase + a * 1024u + off);         \
        _Pragma("unroll")                                                     \
        for (int b = 0; b < 4; ++b)                                           \
            bfr[b] = *(const bf16x8*)(sb_ + bbase + b * 1024u + off);         \
    } while (0)

    #define MFMA16() do {                                                     \
        _Pragma("unroll")                                                     \
        for (int a = 0; a < 4; ++a)                                           \
            _Pragma("unroll")                                                 \
            for (int b = 0; b < 4; ++b)                                       \
                acc[a][b] = __builtin_amdgcn_mfma_f32_16x16x32_bf16(          \
                    afr[a], bfr[b], acc[a][b], 0, 0, 0);                      \
    } while (0)

    int cs = 0;   // ring slot of the CURRENT step (runs mod 3 across tiles)

    // prologue: first tile's steps 0,1 into slots 0,1
    {
        const int gg = 392 * xcd + jj;
        stage3(APtr(gg), BPtr(gg), 0,  sm);
        stage3(APtr(gg), BPtr(gg), 64, sm + SLOT3);
    }

    for (int l = jj; l < 392; l += 64) {
        const int g = 392 * xcd + l;
        const char* Ag = APtr(g);
        const char* Bg = BPtr(g);
        const bool hasNext = (l + 64) < 392;
        const int gn = hasNext ? (g + 64) : g;
        const char* An = APtr(gn);
        const char* Bn = BPtr(gn);

        #pragma unroll
        for (int a = 0; a < 4; ++a)
            #pragma unroll
            for (int b = 0; b < 4; ++b) acc[a][b] = f32x4{0.f, 0.f, 0.f, 0.f};

        #pragma unroll
        for (int t = 0; t < 16; ++t) {
            const char* sb_ = sm + (size_t)cs * SLOT3;
            int ps = cs + 2; if (ps >= 3) ps -= 3;
            char* ns_ = sm + (size_t)ps * SLOT3;

            // counted wait: slot-t loads were issued 2 steps ago
            if (t == 15 && !hasNext) asm volatile("s_waitcnt vmcnt(0)" ::: "memory");
            else                     asm volatile("s_waitcnt vmcnt(3)" ::: "memory");
            __builtin_amdgcn_s_barrier();

            if (t < 14) {
                stage3(Ag, Bg, (t + 2) * 64, ns_);
            } else if (hasNext) {
                stage3(An, Bn, (t - 14) * 64, ns_);
            }
            __builtin_amdgcn_sched_barrier(0);   // pin stage-issue first

            READ8();
            __builtin_amdgcn_s_setprio(1); MFMA16(); __builtin_amdgcn_s_setprio(0);
            cs = (cs == 2) ? 0 : cs + 1;
        }

        // ---- epilogue (next tile's steps 0,1 already in flight/staged)
        const int s  = g >> 6;
        const int kb = (g >> 4) & 3;
        const int qb = g & 15;

        const float* csrc = (g < 1568) ? (xp + (size_t)g * CHUNK)
                                       : (xq + (size_t)(g - 1568) * CHUNK);
        float* cdst = outv + (size_t)g * CHUNK;
        f32x4 cbuf[6];
        #pragma unroll
        for (int i = 0; i < 6; ++i)
            cbuf[i] = *(const f32x4*)(csrc + tid * 4 + i * 2048);

        float q_m[4], q_s[4];
        #pragma unroll
        for (int b = 0; b < 4; ++b) {
            float m = -3.0e38f;
            #pragma unroll
            for (int a = 0; a < 4; ++a)
                #pragma unroll
                for (int r = 0; r < 4; ++r) m = fmaxf(m, acc[a][b][r]);
            float ss = 0.0f;
            #pragma unroll
            for (int a = 0; a < 4; ++a)
                #pragma unroll
                for (int r = 0; r < 4; ++r) ss += __expf(acc[a][b][r] - m);
            #pragma unroll
            for (int off2 = 16; off2 <= 32; off2 <<= 1) {
                float mo = __shfl_xor(m, off2, 64);
                float so = __shfl_xor(ss, off2, 64);
                float nm = fmaxf(m, mo);
                ss = ss * __expf(m - nm) + so * __expf(mo - nm);
                m = nm;
            }
            q_m[b] = m; q_s[b] = ss;
        }

        // diag: tile cond kb == (qb&7)>>1; wave cond wk == ((qb&7)&1)*2 + wq;
        // then a==b, l15>>2 == l4, reg r = lane&3 (compile-time indexed).
        if (kb == ((qb & 7) >> 1) && wk == ((qb & 7) & 1) * 2 + wq) {
            float d = 0.0f;
            const bool lok = ((l15 >> 2) == l4);
            #pragma unroll
            for (int b = 0; b < 4; ++b)
                #pragma unroll
                for (int r = 0; r < 4; ++r)
                    if (lok && r == (lane & 3)) d += acc[b][b][r];
            #pragma unroll
            for (int off2 = 1; off2 < 64; off2 <<= 1) d += __shfl_xor(d, off2, 64);
            if (lane == 0) atomicAdd(out, -d * SCALE);
        }

        // drain cbuf (also retires next tile's prefetched slots), then stores
        asm volatile("s_waitcnt vmcnt(0)" ::: "memory");
        #pragma unroll
        for (int i = 0; i < 6; ++i)
            *(f32x4*)(cdst + tid * 4 + i * 2048) = cbuf[i];

        if (lane < 16) {
            const size_t rowb = (size_t)s * 2048 + (size_t)(qb >= 8) * 1024
                              + (size_t)(qb & 7) * 128 + wq * 64 + lane;
            #pragma unroll
            for (int b = 0; b < 4; ++b)
                part[(rowb + b * 16) * 16 + kb * 4 + wk] = make_float2(q_m[b], q_s[b]);
        }
    }
    #undef READ8
    #undef MFMA16
}

// merge the 16 per-(kb,wk) partials of each row -> lse, accumulate loss
__global__ __launch_bounds__(256) void reduce_kernel(
    const float2* __restrict__ part, float* __restrict__ out)
{
    const int row = blockIdx.x * 256 + threadIdx.x;   // 392*256 = 100352 rows
    const float2* p = part + (size_t)row * 16;
    float m = -3.0e38f;
    float2 q[16];
    #pragma unroll
    for (int i = 0; i < 16; ++i) { q[i] = p[i]; m = fmaxf(m, q[i].x); }
    float ssum = 0.0f;
    #pragma unroll
    for (int i = 0; i < 16; ++i) ssum += q[i].y * __expf(q[i].x - m);
    float v = m + __logf(ssum);
    #pragma unroll
    for (int off = 1; off < 64; off <<= 1) v += __shfl_xor(v, off, 64);
    __shared__ float red[4];
    const int lane = threadIdx.x & 63, w = threadIdx.x >> 6;
    if (lane == 0) red[w] = v;
    __syncthreads();
    if (threadIdx.x == 0)
        atomicAdd(out, (red[0] + red[1] + red[2] + red[3]) * SCALE);
}

extern "C" void kernel_launch(void* const* d_in, const int* in_sizes, int n_in,
                              void* d_out, int out_size, void* d_ws, size_t ws_size,
                              hipStream_t stream)
{
    (void)in_sizes; (void)n_in; (void)out_size; (void)ws_size;
    const float* f  = (const float*)d_in[0];
    const float* x  = (const float*)d_in[1];
    const float* xp = (const float*)d_in[2];
    const float* mt = (const float*)d_in[3];
    const float* mp = (const float*)d_in[4];
    const float* ct = (const float*)d_in[5];
    const float* cp = (const float*)d_in[6];
    float* out = (float*)d_out;

    char* ws = (char*)d_ws;
    const size_t packBytes = (size_t)SDIM * NDIM * DDIM * 2;   // 51.4 MB
    __hip_bfloat16* Km = (__hip_bfloat16*)ws;
    __hip_bfloat16* Qm = (__hip_bfloat16*)(ws + packBytes);
    __hip_bfloat16* Fm = (__hip_bfloat16*)(ws + 2 * packBytes);
    float2* part = (float2*)(ws + 2 * packBytes + (size_t)NDIM * DDIM * 2);

    front_kernel<<<2048, 512, 0, stream>>>(xp, mp, cp, Km, x, mt, ct, Qm, f, Fm, out);
    loss_kernel<<<512, 512, 3 * SLOT3, stream>>>(Fm, Km, Qm, xp, x, out + 1, part, out);
    reduce_kernel<<<392, 256, 0, stream>>>(part, out);
}